// Round 16
// baseline (493.760 us; speedup 1.0000x reference)
//
#include <hip/hip_runtime.h>
#include <hip/hip_bf16.h>
#include <math.h>

#define HIDDEN 4096
#define NH 32
#define NKV 8
#define HD 128
#define QSZ 4096
#define KVSZ 1024
#define QKV_N 6144
#define Bb 2
#define Ss 2048
#define MTOT 4096   // B*S
#define SCALE 0.08838834764831845f
#define SC2 0.12751743299026142f  // SCALE * log2(e); folded into Q at RoPE

typedef __attribute__((ext_vector_type(8))) __bf16 bf16x8;
typedef __attribute__((ext_vector_type(4))) __bf16 bf16x4;
typedef __attribute__((ext_vector_type(4))) float f32x4;

__device__ __forceinline__ f32x4 mfma_bf16(bf16x8 a, bf16x8 b, f32x4 c) {
  return __builtin_amdgcn_mfma_f32_16x16x32_bf16(a, b, c, 0, 0, 0);
}

// global -> LDS direct copy, 16B per lane. LDS dest is wave-uniform base;
// lane l lands at dst + l*16. Global src is per-lane.
__device__ __forceinline__ void gload_lds16(const void* g, void* l) {
  __builtin_amdgcn_global_load_lds((const __attribute__((address_space(1))) void*)g,
                                   (__attribute__((address_space(3))) void*)l, 16, 0, 0);
}

#define VM8() asm volatile("s_waitcnt vmcnt(8)" ::: "memory")
#define VM0() asm volatile("s_waitcnt vmcnt(0)" ::: "memory")
#define BAR() asm volatile("s_barrier" ::: "memory")

template <int N>
__device__ __forceinline__ void vmw() {
  if constexpr (N == 0) asm volatile("s_waitcnt vmcnt(0)" ::: "memory");
  else if constexpr (N == 4) asm volatile("s_waitcnt vmcnt(4)" ::: "memory");
  else if constexpr (N == 5) asm volatile("s_waitcnt vmcnt(5)" ::: "memory");
  else if constexpr (N == 8) asm volatile("s_waitcnt vmcnt(8)" ::: "memory");
  else if constexpr (N == 10) asm volatile("s_waitcnt vmcnt(10)" ::: "memory");
}

// ---------------- elementwise f32 -> bf16 (vectorized) ----------------
__global__ __launch_bounds__(256) void f2b(const float* __restrict__ in,
                                           __bf16* __restrict__ out, long n4) {
  for (long i = (long)blockIdx.x * blockDim.x + threadIdx.x; i < n4;
       i += (long)gridDim.x * blockDim.x) {
    float4 v = ((const float4*)in)[i];
    bf16x4 o = {(__bf16)v.x, (__bf16)v.y, (__bf16)v.z, (__bf16)v.w};
    ((bf16x4*)out)[i] = o;
  }
}

// ---------------- transpose + convert: w[K][N] f32 -> wT[N][K] bf16 ----------------
__global__ __launch_bounds__(256) void transpose_conv(const float* __restrict__ w,
                                                      __bf16* __restrict__ wT,
                                                      int K, int N) {
  __shared__ __bf16 tile[64][65];
  int nb = N >> 6;
  int kt = blockIdx.x / nb, nt = blockIdx.x % nb;
  for (int i = threadIdx.x; i < 64 * 64; i += 256) {
    int kl = i >> 6, nl = i & 63;
    tile[kl][nl] = (__bf16)w[(size_t)(kt * 64 + kl) * N + (nt * 64 + nl)];
  }
  __syncthreads();
  for (int i = threadIdx.x; i < 64 * 64; i += 256) {
    int nl = i >> 6, kl = i & 63;
    wT[(size_t)(nt * 64 + nl) * K + (kt * 64 + kl)] = tile[kl][nl];
  }
}

// ---------------- templated deep-pipelined GEMM: C[M][N] = A * Bt^T (+bias) -------
// 8 waves (2M x 4N). Tile BM=32*MF x BN=64*NF, BK=32. Ring of RING LDS
// buffers, staged DEPTH K-steps ahead via global_load_lds (LPS=MF/4+NF/2
// loads/thread/step). Counted vmcnt ledger (T4): in-loop wait
// vmcnt((DEPTH-1)*LPS) retires exactly step-t's loads; peeled epilogue
// drains (DEPTH-1-j)*LPS -> 0. One raw s_barrier per K-step (it also
// provides WAR protection for the wr slot: all waves are past step t-1's
// reads when they reach the top-of-step-t barrier). 16B-slot swizzle
// slot^=(row>>1)&3 (T2, rule 21). setprio around MFMA clusters (T5). XCD
// chunked swizzle (T1, grid%8==0). A-frags read in two halves of MF/2.
// <8,4,4,3> = O-proj (proven ~61% of dense peak).
// <8,6,4,3> = QKV: 256x384 tile, grid 16x16=256 = ONE balanced pass,
//   ring-4 160KB (AITER fmha precedent for 160KB/workgroup), DEPTH=3
//   matching O-proj's pipeline depth (the DEPTH=2 variant ran 46% peak).
template <int MF, int NF, int RING, int DEPTH>
__global__ __launch_bounds__(512, 1) void gemm_t(const __bf16* __restrict__ A,
                                                 const __bf16* __restrict__ Bt,
                                                 const float* __restrict__ bias,
                                                 void* __restrict__ Cout,
                                                 int M, int N, int K, int out_bf16) {
  constexpr int BM = 32 * MF, BN = 64 * NF;
  constexpr int ABYTES = BM * 64;
  constexpr int BUF = ABYTES + BN * 64;
  constexpr int NA = MF / 4, NB = NF / 2;
  constexpr int LPS = NA + NB;
  constexpr int MH = MF / 2;
  extern __shared__ char smem[];           // RING * BUF bytes
  const int tid = threadIdx.x;
  const int wid = tid >> 6, lane = tid & 63;
  const int lr = lane & 15, hi = lane >> 4;
  const int wm = wid >> 2, wn = wid & 3;
  const int nbn = N / BN;
  const int nwg = gridDim.x;
  const int tile = ((blockIdx.x & 7) * (nwg >> 3)) + (blockIdx.x >> 3);  // T1
  const int bm = tile / nbn, bn = tile % nbn;
  const int m0 = bm * BM, n0 = bn * BN;

  const int row0 = tid >> 2, cg = tid & 3;
  const int cgs = cg ^ ((row0 >> 1) & 3);
  const __bf16* pA[NA];
  const __bf16* pB[NB];
#pragma unroll
  for (int i = 0; i < NA; i++)
    pA[i] = A + (size_t)(m0 + row0 + i * 128) * K + cgs * 8;
#pragma unroll
  for (int j = 0; j < NB; j++)
    pB[j] = Bt + (size_t)(n0 + row0 + j * 128) * K + cgs * 8;

  auto stage = [&](int slot, int ts) {
    char* d = smem + (size_t)(slot * BUF) + (wid << 10);
#pragma unroll
    for (int i = 0; i < NA; i++) gload_lds16(pA[i] + (size_t)ts * 32, d + i * 8192);
#pragma unroll
    for (int j = 0; j < NB; j++)
      gload_lds16(pB[j] + (size_t)ts * 32, d + ABYTES + j * 8192);
  };

  int aoff[MF], boff[NF];
#pragma unroll
  for (int fr = 0; fr < MF; fr++) {
    int ra = wm * (16 * MF) + fr * 16 + lr;
    aoff[fr] = ra * 64 + ((hi ^ ((ra >> 1) & 3)) << 4);
  }
#pragma unroll
  for (int fc = 0; fc < NF; fc++) {
    int rb = wn * (16 * NF) + fc * 16 + lr;
    boff[fc] = ABYTES + rb * 64 + ((hi ^ ((rb >> 1) & 3)) << 4);
  }

  const f32x4 fz = {0.f, 0.f, 0.f, 0.f};
  f32x4 acc[MF][NF];
#pragma unroll
  for (int i = 0; i < MF; i++)
#pragma unroll
    for (int j = 0; j < NF; j++) acc[i][j] = fz;

  const int nsteps = K >> 5;  // K/32, >= DEPTH+1

  // STEP: frag reads + MFMA for K-step in slot rd; optionally stage k-step
  // ts into slot wr. A-frags read in two halves of MH to cap registers.
  auto STEP = [&](int rd, int wr, int ts, bool do_stage) {
    const char* base = smem + (size_t)(rd * BUF);
    if (do_stage) stage(wr, ts);
    bf16x8 bfr[NF], afr[MH];
#pragma unroll
    for (int fc = 0; fc < NF; fc++) bfr[fc] = *(const bf16x8*)(base + boff[fc]);
#pragma unroll
    for (int fr = 0; fr < MH; fr++) afr[fr] = *(const bf16x8*)(base + aoff[fr]);
    __builtin_amdgcn_s_setprio(1);
#pragma unroll
    for (int fr = 0; fr < MH; fr++)
#pragma unroll
      for (int fc = 0; fc < NF; fc++)
        acc[fr][fc] = mfma_bf16(afr[fr], bfr[fc], acc[fr][fc]);
    __builtin_amdgcn_s_setprio(0);
#pragma unroll
    for (int fr = 0; fr < MH; fr++) afr[fr] = *(const bf16x8*)(base + aoff[MH + fr]);
    __builtin_amdgcn_s_setprio(1);
#pragma unroll
    for (int fr = 0; fr < MH; fr++)
#pragma unroll
      for (int fc = 0; fc < NF; fc++)
        acc[MH + fr][fc] = mfma_bf16(afr[fr], bfr[fc], acc[MH + fr][fc]);
    __builtin_amdgcn_s_setprio(0);
  };

  // prologue: stage k-steps 0..DEPTH-1 into slots 0..DEPTH-1
#pragma unroll
  for (int d = 0; d < DEPTH; d++) stage(d, d);

  int rd = 0, wr = DEPTH % RING;
  auto adv = [&](int& s) { s = (s + 1 == RING) ? 0 : s + 1; };

  int t = 0;
  for (; t < nsteps - DEPTH; ++t) {
    vmw<(DEPTH - 1) * LPS>();  // retire step t's LPS loads; newer stay in flight
    BAR();                     // all waves' step-t loads landed; WAR on wr slot
    STEP(rd, wr, t + DEPTH, true);
    adv(rd);
    adv(wr);
  }
  // peeled drain
  {
    vmw<(DEPTH - 1) * LPS>(); BAR(); STEP(rd, wr, 0, false); adv(rd); ++t;
  }
  if constexpr (DEPTH >= 2) {
    vmw<(DEPTH - 2) * LPS>(); BAR(); STEP(rd, wr, 0, false); adv(rd); ++t;
  }
  if constexpr (DEPTH >= 3) {
    vmw<(DEPTH - 3) * LPS>(); BAR(); STEP(rd, wr, 0, false); adv(rd); ++t;
  }

  float bv[NF];
#pragma unroll
  for (int fc = 0; fc < NF; fc++)
    bv[fc] = bias ? bias[n0 + wn * (16 * NF) + fc * 16 + lr] : 0.f;
#pragma unroll
  for (int fr = 0; fr < MF; fr++) {
    int row_base = m0 + wm * (16 * MF) + fr * 16 + hi * 4;
#pragma unroll
    for (int fc = 0; fc < NF; fc++) {
      int col = n0 + wn * (16 * NF) + fc * 16 + lr;
#pragma unroll
      for (int r = 0; r < 4; r++) {
        int row = row_base + r;
        float v = acc[fr][fc][r] + bv[fc];
        if (out_bf16)
          ((__bf16*)Cout)[(size_t)row * N + col] = (__bf16)v;
        else
          ((float*)Cout)[(size_t)row * N + col] = v;
      }
    }
  }
}

// ---------------- RoPE for q and k (Q pre-scaled by SCALE*log2e) ----------------
__global__ __launch_bounds__(256) void rope_qk(const __bf16* __restrict__ qkv,
                                               const int* __restrict__ pos,
                                               __bf16* __restrict__ Qo,
                                               __bf16* __restrict__ Ko) {
  int bs = blockIdx.x;
  int b = bs / Ss, s = bs % Ss;
  float p = (float)pos[s];
  const __bf16* src = qkv + (size_t)bs * QKV_N;
  for (int t = threadIdx.x; t < (NH + NKV) * 64; t += 256) {
    int head = t >> 6, i = t & 63;
    float inv = exp2f((float)i * (-13.287712379549449f / 64.f));
    float sn, cs;
    sincosf(p * inv, &sn, &cs);
    if (head < NH) {
      float x1 = (float)src[head * HD + i];
      float x2 = (float)src[head * HD + i + 64];
      __bf16* dst = Qo + ((size_t)(b * NH + head) * Ss + s) * HD;
      dst[i] = (__bf16)((x1 * cs - x2 * sn) * SC2);
      dst[i + 64] = (__bf16)((x2 * cs + x1 * sn) * SC2);
    } else {
      int kh = head - NH;
      float x1 = (float)src[QSZ + kh * HD + i];
      float x2 = (float)src[QSZ + kh * HD + i + 64];
      __bf16* dst = Ko + ((size_t)(b * NKV + kh) * Ss + s) * HD;
      dst[i] = (__bf16)(x1 * cs - x2 * sn);
      dst[i + 64] = (__bf16)(x2 * cs + x1 * sn);
    }
  }
}

// ---------------- V transpose: qkv v-part -> Vt[B][KVH][D][S] ----------------
__global__ __launch_bounds__(256) void vtrans(const __bf16* __restrict__ qkv,
                                              __bf16* __restrict__ Vt) {
  __shared__ __bf16 tile[128][65];
  int bid = blockIdx.x;
  int st_ = bid & 31;
  int kvh = (bid >> 5) & 7;
  int b = bid >> 8;
  int s0 = st_ * 64;
  const __bf16* src = qkv + (size_t)(b * Ss) * QKV_N + (QSZ + KVSZ) + kvh * HD;
  for (int i = threadIdx.x; i < 64 * 128; i += 256) {
    int sl = i >> 7, d = i & 127;
    tile[d][sl] = src[(size_t)(s0 + sl) * QKV_N + d];
  }
  __syncthreads();
  __bf16* dst = Vt + (size_t)(b * NKV + kvh) * HD * Ss;
  for (int i = threadIdx.x; i < 64 * 128; i += 256) {
    int dl = i >> 6, sl = i & 63;
    dst[(size_t)dl * Ss + s0 + sl] = tile[dl][sl];
  }
}

// ---------------- causal flash attention (v9: pair-balanced grid) ----------------
// Each block processes the causal PAIR of q-tiles (qb=15-j heavy, then qb=j
// light) -> 34 chunks for EVERY block; grid B*NH*8 = 512 = 2 blocks/CU =
// one perfectly balanced pass (this was the v4-v8 ~215us invariant; fixed
// 219 -> ~150us). Inner loop: counted-vmcnt ledger (T4), 2 raw barriers,
// setprio (T5), swizzled K/V/P (T2).
__global__ __launch_bounds__(256, 2) void attn_fwd(const __bf16* __restrict__ Q,
                                                   const __bf16* __restrict__ Kk,
                                                   const __bf16* __restrict__ Vt,
                                                   __bf16* __restrict__ Oa) {
  __shared__ __bf16 Kl[2][64 * 128];   // [64 keys][128 d], 16B slots ^= (row&15)
  __shared__ __bf16 Vl[2][128 * 64];   // [128 d][64 keys], 16B slots ^= (row&7)
  __shared__ __bf16 Pl[4][32 * 64];    // per-wave [32 q][64 keys], ^= (row&7)
  const int tid = threadIdx.x, wave = tid >> 6, lane = tid & 63;
  const int bid = blockIdx.x;
  const int b = bid / (NH * 8);
  const int h = (bid / 8) % NH;
  const int jj = bid & 7;              // pair index: q-tiles (15-jj, jj)
  const int kvh = h >> 2;
  const int lr = lane & 15, hi = lane >> 4;
  const f32x4 fz = {0.f, 0.f, 0.f, 0.f};

  const __bf16* kbase = Kk + (size_t)(b * NKV + kvh) * Ss * HD;
  const __bf16* vbase = Vt + (size_t)(b * NKV + kvh) * HD * Ss;

  // staging coords (segment-invariant): waves 0-1 stage K, waves 2-3 stage V.
  const __bf16* srun;
  int soff[8], sldso[8], sstep;
  char* ldsbase;
  if (wave < 2) {
#pragma unroll
    for (int i = 0; i < 8; i++) {
      int cidx = wave * 8 + i;
      int r = cidx * 4 + (lane >> 4);  // key row 0..63
      soff[i] = r * HD + (((lane & 15) ^ (r & 15)) << 3);
      sldso[i] = cidx << 10;
    }
    sstep = 64 * HD;
    ldsbase = (char*)Kl;
  } else {
#pragma unroll
    for (int i = 0; i < 8; i++) {
      int cc = (wave - 2) * 8 + i;
      int r = cc * 8 + (lane >> 3);    // d row 0..127
      soff[i] = r * Ss + (((lane & 7) ^ (r & 7)) << 3);
      sldso[i] = cc << 10;
    }
    sstep = 64;
    ldsbase = (char*)Vl;
  }

  auto STAGE = [&](int buf) {
    char* dbase = ldsbase + (buf << 14);
#pragma unroll
    for (int i = 0; i < 8; i++) gload_lds16(srun + soff[i], dbase + sldso[i]);
    srun += sstep;
  };

  char* pw = (char*)Pl[wave];

  for (int s = 0; s < 2; ++s) {
    const int qb = s ? jj : (15 - jj);  // heavy tile first (light KV subset, L2-warm)
    const int q0 = qb * 128;
    const int wrow0 = q0 + wave * 32;   // this wave's first q row

    // Q rows q0 + wave*32 + g*16 + lr (pre-scaled by SC2 -> scores in log2)
    bf16x8 qf[2][4];
#pragma unroll
    for (int g = 0; g < 2; g++) {
      const __bf16* qbase =
          Q + ((size_t)(b * NH + h) * Ss + wrow0 + g * 16 + lr) * HD;
#pragma unroll
      for (int dc = 0; dc < 4; dc++)
        qf[g][dc] = *(const bf16x8*)(qbase + dc * 32 + hi * 8);
    }

    f32x4 oacc[2][8];
#pragma unroll
    for (int g = 0; g < 2; g++)
#pragma unroll
      for (int i = 0; i < 8; i++) oacc[g][i] = fz;
    float m_[2] = {-1e30f, -1e30f}, l_[2] = {0.f, 0.f};

    srun = (wave < 2) ? kbase : vbase;  // ledger reset per segment
    STAGE(0);                           // chunk 0 in flight (8 loads)
    int cur = 0;
    const int nc = 2 * qb + 2;          // chunks of 64 keys

    for (int c = 0; c < nc; ++c) {
      // T4 ledger: issue chunk c+1, then retire exactly chunk c's 8 loads.
      if (c + 1 < nc) {
        STAGE(cur ^ 1);
        VM8();
      } else {
        VM0();
      }
      BAR();                            // chunk c visible to all waves

      const int k0 = c * 64;
      const bool active = (k0 <= wrow0 + 31);  // wave-uniform

      if (active) {
        const char* Kb = (const char*)Kl[cur];
        const char* Vb = (const char*)Vl[cur];

        // S^T = K Q^T : lane (lr,hi) gets keys 16t+4hi+r of q-rows g*16+lr.
        f32x4 st[2][4];
#pragma unroll
        for (int t = 0; t < 4; t++) { st[0][t] = fz; st[1][t] = fz; }
        __builtin_amdgcn_s_setprio(1);
#pragma unroll
        for (int t = 0; t < 4; t++) {
#pragma unroll
          for (int dc = 0; dc < 4; dc++) {
            const bf16x8 kf = *(const bf16x8*)(Kb + (t * 16 + lr) * 256 +
                                               (((dc * 4 + hi) ^ lr) << 4));
            st[0][t] = mfma_bf16(kf, qf[0][dc], st[0][t]);
            st[1][t] = mfma_bf16(kf, qf[1][dc], st[1][t]);
          }
        }
        __builtin_amdgcn_s_setprio(0);

        const bool needMask = (k0 + 63 > wrow0);  // wave-uniform
        float s2[2][4][4];
        float mx[2];
#pragma unroll
        for (int g = 0; g < 2; g++) {
          const int rel = wrow0 + g * 16 + lr - k0;
          float m = -1e30f;
#pragma unroll
          for (int t = 0; t < 4; t++)
#pragma unroll
            for (int r = 0; r < 4; r++) {
              float v = st[g][t][r];  // log2 domain (Q pre-scaled)
              if (needMask && (16 * t + 4 * hi + r > rel)) v = -1e30f;
              s2[g][t][r] = v;
              m = fmaxf(m, v);
            }
          m = fmaxf(m, __shfl_xor(m, 16, 64));
          m = fmaxf(m, __shfl_xor(m, 32, 64));
          mx[g] = m;
        }

        // defer-max (T13): O-rescale only when running max grows by > 8
        if (__any((mx[0] > m_[0] + 8.f) || (mx[1] > m_[1] + 8.f))) {
#pragma unroll
          for (int g = 0; g < 2; g++) {
            float mn = fmaxf(m_[g], mx[g]);
            float al = exp2f(m_[g] - mn);
            l_[g] *= al;
            m_[g] = mn;
            float alr[4];
#pragma unroll
            for (int r = 0; r < 4; r++) alr[r] = __shfl(al, hi * 4 + r, 64);
#pragma unroll
            for (int dt = 0; dt < 8; dt++)
#pragma unroll
              for (int r = 0; r < 4; r++) oacc[g][dt][r] *= alr[r];
          }
        }

#pragma unroll
        for (int g = 0; g < 2; g++) {
          float rs = 0.f;
          const int rp = g * 16 + lr;  // rp&7 == lr&7
#pragma unroll
          for (int t = 0; t < 4; t++) {
            float p0 = exp2f(s2[g][t][0] - m_[g]), p1 = exp2f(s2[g][t][1] - m_[g]);
            float p2 = exp2f(s2[g][t][2] - m_[g]), p3 = exp2f(s2[g][t][3] - m_[g]);
            rs += (p0 + p1) + (p2 + p3);
            bf16x4 pv = {(__bf16)p0, (__bf16)p1, (__bf16)p2, (__bf16)p3};
            *(bf16x4*)(pw + rp * 128 + (((2 * t + (hi >> 1)) ^ (lr & 7)) << 4) +
                       (hi & 1) * 8) = pv;
          }
          rs += __shfl_xor(rs, 16, 64);
          rs += __shfl_xor(rs, 32, 64);
          l_[g] += rs;
        }

        // PV: vf read ONCE per (dt,kc), used by both q-groups.
        bf16x8 pf[2][2];
#pragma unroll
        for (int g = 0; g < 2; g++)
#pragma unroll
          for (int kc = 0; kc < 2; kc++)
            pf[g][kc] = *(const bf16x8*)(pw + (g * 16 + lr) * 128 +
                                         (((4 * kc + hi) ^ (lr & 7)) << 4));
        __builtin_amdgcn_s_setprio(1);
#pragma unroll
        for (int dt = 0; dt < 8; dt++) {
#pragma unroll
          for (int kc = 0; kc < 2; kc++) {
            const bf16x8 vf = *(const bf16x8*)(Vb + (dt * 16 + lr) * 128 +
                                               (((kc * 4 + hi) ^ (lr & 7)) << 4));
            oacc[0][dt] = mfma_bf16(pf[0][kc], vf, oacc[0][dt]);
            oacc[1][dt] = mfma_bf16(pf[1][kc], vf, oacc[1][dt]);
          }
        }
        __builtin_amdgcn_s_setprio(0);
      }

      BAR();  // WAR: all waves done reading buf cur (next STAGE overwrites)
      cur ^= 1;
    }

    // epilogue for this q-tile
#pragma unroll
    for (int g = 0; g < 2; g++) {
      float rl[4];
#pragma unroll
      for (int r = 0; r < 4; r++) rl[r] = __shfl(l_[g], hi * 4 + r, 64);
#pragma unroll
      for (int dt = 0; dt < 8; dt++) {
#pragma unroll
        for (int r = 0; r < 4; r++) {
          int row = wrow0 + g * 16 + hi * 4 + r;
          Oa[((size_t)(b * Ss) + row) * QSZ + h * HD + dt * 16 + lr] =
              (__bf16)(oacc[g][dt][r] / rl[r]);
        }
      }
    }
  }
}

extern "C" void kernel_launch(void* const* d_in, const int* in_sizes, int n_in,
                              void* d_out, int out_size, void* d_ws, size_t ws_size,
                              hipStream_t stream) {
  const int* positions = (const int*)d_in[0];
  const float* hidden = (const float*)d_in[1];
  const float* w_qkv = (const float*)d_in[2];
  const float* b_qkv = (const float*)d_in[3];
  const float* w_o = (const float*)d_in[4];
  float* out = (float*)d_out;

  char* ws = (char*)d_ws;
  __bf16* hs = (__bf16*)(ws);
  __bf16* wqkvT = (__bf16*)(ws + 33554432);
  __bf16* woT = (__bf16*)(ws + 83886080);
  __bf16* qkv = (__bf16*)(ws + 117440512);
  __bf16* q = (__bf16*)(ws + 167772160);
  __bf16* k = (__bf16*)(ws + 201326592);
  __bf16* vt = (__bf16*)(ws + 209715200);
  __bf16* attn = hs;  // hs dead after gemm1; reuse for attention output

  f2b<<<2048, 256, 0, stream>>>(hidden, hs, (long)MTOT * HIDDEN / 4);
  transpose_conv<<<(HIDDEN / 64) * (QKV_N / 64), 256, 0, stream>>>(w_qkv, wqkvT, HIDDEN, QKV_N);
  transpose_conv<<<(QSZ / 64) * (HIDDEN / 64), 256, 0, stream>>>(w_o, woT, QSZ, HIDDEN);
  // QKV: tile 256x384, grid 16*16=256 = ONE balanced pass, ring-4 (160KB),
  // DEPTH=3 (matches O-proj's proven pipeline depth)
  gemm_t<8, 6, 4, 3><<<(MTOT / 256) * (QKV_N / 384), 512, 163840, stream>>>(
      hs, wqkvT, b_qkv, qkv, MTOT, QKV_N, HIDDEN, 1);
  rope_qk<<<Bb * Ss, 256, 0, stream>>>(qkv, positions, q, k);
  vtrans<<<Bb * NKV * (Ss / 64), 256, 0, stream>>>(qkv, vt);
  // attn: pair-balanced grid, 512 blocks = one balanced pass at 2 blocks/CU
  attn_fwd<<<Bb * NH * 8, 256, 0, stream>>>(q, k, vt, attn);
  // O-proj: tile 256x256, grid 16*16=256 = 1 balanced pass, ring-4 (128KB)
  gemm_t<8, 4, 4, 3><<<(MTOT / 256) * (QSZ / 256), 512, 131072, stream>>>(
      attn, woT, nullptr, out, MTOT, QSZ, QSZ, 0);
}

// Round 18
// 491.059 us; speedup vs baseline: 1.0055x; 1.0055x over previous
//
#include <hip/hip_runtime.h>
#include <hip/hip_bf16.h>
#include <math.h>

#define HIDDEN 4096
#define NH 32
#define NKV 8
#define HD 128
#define QSZ 4096
#define KVSZ 1024
#define QKV_N 6144
#define Bb 2
#define Ss 2048
#define MTOT 4096   // B*S
#define SCALE 0.08838834764831845f
#define SC2 0.12751743299026142f  // SCALE * log2(e); folded into Q at RoPE

typedef __attribute__((ext_vector_type(8))) __bf16 bf16x8;
typedef __attribute__((ext_vector_type(4))) __bf16 bf16x4;
typedef __attribute__((ext_vector_type(4))) float f32x4;

__device__ __forceinline__ f32x4 mfma_bf16(bf16x8 a, bf16x8 b, f32x4 c) {
  return __builtin_amdgcn_mfma_f32_16x16x32_bf16(a, b, c, 0, 0, 0);
}

// global -> LDS direct copy, 16B per lane. LDS dest is wave-uniform base;
// lane l lands at dst + l*16. Global src is per-lane.
__device__ __forceinline__ void gload_lds16(const void* g, void* l) {
  __builtin_amdgcn_global_load_lds((const __attribute__((address_space(1))) void*)g,
                                   (__attribute__((address_space(3))) void*)l, 16, 0, 0);
}

#define VM8() asm volatile("s_waitcnt vmcnt(8)" ::: "memory")
#define VM0() asm volatile("s_waitcnt vmcnt(0)" ::: "memory")
#define BAR() asm volatile("s_barrier" ::: "memory")

template <int N>
__device__ __forceinline__ void vmw() {
  if constexpr (N == 0) asm volatile("s_waitcnt vmcnt(0)" ::: "memory");
  else if constexpr (N == 4) asm volatile("s_waitcnt vmcnt(4)" ::: "memory");
  else if constexpr (N == 5) asm volatile("s_waitcnt vmcnt(5)" ::: "memory");
  else if constexpr (N == 8) asm volatile("s_waitcnt vmcnt(8)" ::: "memory");
  else if constexpr (N == 10) asm volatile("s_waitcnt vmcnt(10)" ::: "memory");
}

// ---------------- elementwise f32 -> bf16 (vectorized) ----------------
__global__ __launch_bounds__(256) void f2b(const float* __restrict__ in,
                                           __bf16* __restrict__ out, long n4) {
  for (long i = (long)blockIdx.x * blockDim.x + threadIdx.x; i < n4;
       i += (long)gridDim.x * blockDim.x) {
    float4 v = ((const float4*)in)[i];
    bf16x4 o = {(__bf16)v.x, (__bf16)v.y, (__bf16)v.z, (__bf16)v.w};
    ((bf16x4*)out)[i] = o;
  }
}

// ---------------- transpose + convert: w[K][N] f32 -> wT[N][K] bf16 ----------------
__global__ __launch_bounds__(256) void transpose_conv(const float* __restrict__ w,
                                                      __bf16* __restrict__ wT,
                                                      int K, int N) {
  __shared__ __bf16 tile[64][65];
  int nb = N >> 6;
  int kt = blockIdx.x / nb, nt = blockIdx.x % nb;
  for (int i = threadIdx.x; i < 64 * 64; i += 256) {
    int kl = i >> 6, nl = i & 63;
    tile[kl][nl] = (__bf16)w[(size_t)(kt * 64 + kl) * N + (nt * 64 + nl)];
  }
  __syncthreads();
  for (int i = threadIdx.x; i < 64 * 64; i += 256) {
    int nl = i >> 6, kl = i & 63;
    wT[(size_t)(nt * 64 + nl) * K + (kt * 64 + kl)] = tile[kl][nl];
  }
}

// ---------------- templated deep-pipelined GEMM: C[M][N] = A * Bt^T (+bias) -------
// 8 waves (2M x 4N). Tile BM=32*MF x BN=64*NF, BK=32. Ring of RING LDS
// buffers, staged DEPTH K-steps ahead via global_load_lds (LPS=MF/4+NF/2
// loads/thread/step). Counted vmcnt ledger (T4): in-loop wait
// vmcnt((DEPTH-1)*LPS) retires exactly step-t's loads; peeled epilogue
// drains (DEPTH-1-j)*LPS -> 0. One raw s_barrier per K-step (also WAR
// protection for the wr slot: all waves finished step t-1's reads before
// passing the top-of-step-t barrier). 16B-slot swizzle slot^=(row>>1)&3
// (T2, rule 21). setprio around MFMA clusters (T5). XCD chunked swizzle
// (T1, grid%8==0). A-frags read in two halves of MF/2.
// <8,6,3,2> = QKV: 256x384 tile, BUF 40KB, ring-3 120KB, grid 16x16=256 =
//   ONE balanced pass (proven 180us / 1.15PF / MfmaUtil 51). Round 16/17
//   variants (DEPTH=3 @160KB; 2-blocks/CU @<4,6>) were neutral/broken.
// <8,4,4,3> = O-proj: 256x256, ring-4 128KB, grid 256 (proven ~61% peak).
template <int MF, int NF, int RING, int DEPTH>
__global__ __launch_bounds__(512, 1) void gemm_t(const __bf16* __restrict__ A,
                                                 const __bf16* __restrict__ Bt,
                                                 const float* __restrict__ bias,
                                                 void* __restrict__ Cout,
                                                 int M, int N, int K, int out_bf16) {
  constexpr int BM = 32 * MF, BN = 64 * NF;
  constexpr int ABYTES = BM * 64;
  constexpr int BUF = ABYTES + BN * 64;
  constexpr int NA = MF / 4, NB = NF / 2;
  constexpr int LPS = NA + NB;
  constexpr int MH = MF / 2;
  extern __shared__ char smem[];           // RING * BUF bytes
  const int tid = threadIdx.x;
  const int wid = tid >> 6, lane = tid & 63;
  const int lr = lane & 15, hi = lane >> 4;
  const int wm = wid >> 2, wn = wid & 3;
  const int nbn = N / BN;
  const int nwg = gridDim.x;
  const int tile = ((blockIdx.x & 7) * (nwg >> 3)) + (blockIdx.x >> 3);  // T1
  const int bm = tile / nbn, bn = tile % nbn;
  const int m0 = bm * BM, n0 = bn * BN;

  const int row0 = tid >> 2, cg = tid & 3;
  const int cgs = cg ^ ((row0 >> 1) & 3);
  const __bf16* pA[NA];
  const __bf16* pB[NB];
#pragma unroll
  for (int i = 0; i < NA; i++)
    pA[i] = A + (size_t)(m0 + row0 + i * 128) * K + cgs * 8;
#pragma unroll
  for (int j = 0; j < NB; j++)
    pB[j] = Bt + (size_t)(n0 + row0 + j * 128) * K + cgs * 8;

  auto stage = [&](int slot, int ts) {
    char* d = smem + (size_t)(slot * BUF) + (wid << 10);
#pragma unroll
    for (int i = 0; i < NA; i++) gload_lds16(pA[i] + (size_t)ts * 32, d + i * 8192);
#pragma unroll
    for (int j = 0; j < NB; j++)
      gload_lds16(pB[j] + (size_t)ts * 32, d + ABYTES + j * 8192);
  };

  int aoff[MF], boff[NF];
#pragma unroll
  for (int fr = 0; fr < MF; fr++) {
    int ra = wm * (16 * MF) + fr * 16 + lr;
    aoff[fr] = ra * 64 + ((hi ^ ((ra >> 1) & 3)) << 4);
  }
#pragma unroll
  for (int fc = 0; fc < NF; fc++) {
    int rb = wn * (16 * NF) + fc * 16 + lr;
    boff[fc] = ABYTES + rb * 64 + ((hi ^ ((rb >> 1) & 3)) << 4);
  }

  const f32x4 fz = {0.f, 0.f, 0.f, 0.f};
  f32x4 acc[MF][NF];
#pragma unroll
  for (int i = 0; i < MF; i++)
#pragma unroll
    for (int j = 0; j < NF; j++) acc[i][j] = fz;

  const int nsteps = K >> 5;  // K/32, >= DEPTH+1

  // STEP: frag reads + MFMA for K-step in slot rd; optionally stage k-step
  // ts into slot wr. A-frags read in two halves of MH to cap registers.
  auto STEP = [&](int rd, int wr, int ts, bool do_stage) {
    const char* base = smem + (size_t)(rd * BUF);
    if (do_stage) stage(wr, ts);
    bf16x8 bfr[NF], afr[MH];
#pragma unroll
    for (int fc = 0; fc < NF; fc++) bfr[fc] = *(const bf16x8*)(base + boff[fc]);
#pragma unroll
    for (int fr = 0; fr < MH; fr++) afr[fr] = *(const bf16x8*)(base + aoff[fr]);
    __builtin_amdgcn_s_setprio(1);
#pragma unroll
    for (int fr = 0; fr < MH; fr++)
#pragma unroll
      for (int fc = 0; fc < NF; fc++)
        acc[fr][fc] = mfma_bf16(afr[fr], bfr[fc], acc[fr][fc]);
    __builtin_amdgcn_s_setprio(0);
#pragma unroll
    for (int fr = 0; fr < MH; fr++) afr[fr] = *(const bf16x8*)(base + aoff[MH + fr]);
    __builtin_amdgcn_s_setprio(1);
#pragma unroll
    for (int fr = 0; fr < MH; fr++)
#pragma unroll
      for (int fc = 0; fc < NF; fc++)
        acc[MH + fr][fc] = mfma_bf16(afr[fr], bfr[fc], acc[MH + fr][fc]);
    __builtin_amdgcn_s_setprio(0);
  };

  // prologue: stage k-steps 0..DEPTH-1 into slots 0..DEPTH-1
#pragma unroll
  for (int d = 0; d < DEPTH; d++) stage(d, d);

  int rd = 0, wr = DEPTH % RING;
  auto adv = [&](int& s) { s = (s + 1 == RING) ? 0 : s + 1; };

  int t = 0;
  for (; t < nsteps - DEPTH; ++t) {
    vmw<(DEPTH - 1) * LPS>();  // retire step t's LPS loads; newer stay in flight
    BAR();                     // all waves' step-t loads landed; WAR on wr slot
    STEP(rd, wr, t + DEPTH, true);
    adv(rd);
    adv(wr);
  }
  // peeled drain
  {
    vmw<(DEPTH - 1) * LPS>(); BAR(); STEP(rd, wr, 0, false); adv(rd); ++t;
  }
  if constexpr (DEPTH >= 2) {
    vmw<(DEPTH - 2) * LPS>(); BAR(); STEP(rd, wr, 0, false); adv(rd); ++t;
  }
  if constexpr (DEPTH >= 3) {
    vmw<(DEPTH - 3) * LPS>(); BAR(); STEP(rd, wr, 0, false); adv(rd); ++t;
  }

  float bv[NF];
#pragma unroll
  for (int fc = 0; fc < NF; fc++)
    bv[fc] = bias ? bias[n0 + wn * (16 * NF) + fc * 16 + lr] : 0.f;
#pragma unroll
  for (int fr = 0; fr < MF; fr++) {
    int row_base = m0 + wm * (16 * MF) + fr * 16 + hi * 4;
#pragma unroll
    for (int fc = 0; fc < NF; fc++) {
      int col = n0 + wn * (16 * NF) + fc * 16 + lr;
#pragma unroll
      for (int r = 0; r < 4; r++) {
        int row = row_base + r;
        float v = acc[fr][fc][r] + bv[fc];
        if (out_bf16)
          ((__bf16*)Cout)[(size_t)row * N + col] = (__bf16)v;
        else
          ((float*)Cout)[(size_t)row * N + col] = v;
      }
    }
  }
}

// ---------------- RoPE cos/sin table: tab[s][i] = (cos, sin) ----------------
// 131k sincos total (vs 10.5M per-element in rope_qk before) -- m205 lesson:
// precompute trig tables, don't evaluate libm per element.
__global__ __launch_bounds__(64) void rope_tab(const int* __restrict__ pos,
                                               float* __restrict__ tab) {
  int s = blockIdx.x, i = threadIdx.x;  // 64 threads
  float p = (float)pos[s];
  float inv = exp2f((float)i * (-13.287712379549449f / 64.f));
  float sn, cs;
  sincosf(p * inv, &sn, &cs);
  ((float2*)tab)[s * 64 + i] = make_float2(cs, sn);
}

// ---------------- RoPE for q and k (table-based; Q pre-scaled by SC2) -------------
__global__ __launch_bounds__(256) void rope_qk(const __bf16* __restrict__ qkv,
                                               const float* __restrict__ tab,
                                               __bf16* __restrict__ Qo,
                                               __bf16* __restrict__ Ko) {
  int bs = blockIdx.x;
  int b = bs / Ss, s = bs % Ss;
  const __bf16* src = qkv + (size_t)bs * QKV_N;
  const float2* trow = (const float2*)tab + s * 64;
  for (int t = threadIdx.x; t < (NH + NKV) * 64; t += 256) {
    int head = t >> 6, i = t & 63;
    float2 cssn = trow[i];
    float cs = cssn.x, sn = cssn.y;
    if (head < NH) {
      float x1 = (float)src[head * HD + i];
      float x2 = (float)src[head * HD + i + 64];
      __bf16* dst = Qo + ((size_t)(b * NH + head) * Ss + s) * HD;
      dst[i] = (__bf16)((x1 * cs - x2 * sn) * SC2);
      dst[i + 64] = (__bf16)((x2 * cs + x1 * sn) * SC2);
    } else {
      int kh = head - NH;
      float x1 = (float)src[QSZ + kh * HD + i];
      float x2 = (float)src[QSZ + kh * HD + i + 64];
      __bf16* dst = Ko + ((size_t)(b * NKV + kh) * Ss + s) * HD;
      dst[i] = (__bf16)(x1 * cs - x2 * sn);
      dst[i + 64] = (__bf16)(x2 * cs + x1 * sn);
    }
  }
}

// ---------------- V transpose: qkv v-part -> Vt[B][KVH][D][S] ----------------
__global__ __launch_bounds__(256) void vtrans(const __bf16* __restrict__ qkv,
                                              __bf16* __restrict__ Vt) {
  __shared__ __bf16 tile[128][65];
  int bid = blockIdx.x;
  int st_ = bid & 31;
  int kvh = (bid >> 5) & 7;
  int b = bid >> 8;
  int s0 = st_ * 64;
  const __bf16* src = qkv + (size_t)(b * Ss) * QKV_N + (QSZ + KVSZ) + kvh * HD;
  for (int i = threadIdx.x; i < 64 * 128; i += 256) {
    int sl = i >> 7, d = i & 127;
    tile[d][sl] = src[(size_t)(s0 + sl) * QKV_N + d];
  }
  __syncthreads();
  __bf16* dst = Vt + (size_t)(b * NKV + kvh) * HD * Ss;
  for (int i = threadIdx.x; i < 64 * 128; i += 256) {
    int dl = i >> 6, sl = i & 63;
    dst[(size_t)dl * Ss + s0 + sl] = tile[dl][sl];
  }
}

// ---------------- causal flash attention (v9: pair-balanced grid) ----------------
// Each block processes the causal PAIR of q-tiles (qb=15-j heavy, then qb=j
// light) -> 34 chunks for EVERY block; grid B*NH*8 = 512 = 2 blocks/CU =
// one perfectly balanced pass. Inner loop: counted-vmcnt ledger (T4), 2 raw
// barriers, setprio (T5), swizzled K/V/P (T2).
__global__ __launch_bounds__(256, 2) void attn_fwd(const __bf16* __restrict__ Q,
                                                   const __bf16* __restrict__ Kk,
                                                   const __bf16* __restrict__ Vt,
                                                   __bf16* __restrict__ Oa) {
  __shared__ __bf16 Kl[2][64 * 128];   // [64 keys][128 d], 16B slots ^= (row&15)
  __shared__ __bf16 Vl[2][128 * 64];   // [128 d][64 keys], 16B slots ^= (row&7)
  __shared__ __bf16 Pl[4][32 * 64];    // per-wave [32 q][64 keys], ^= (row&7)
  const int tid = threadIdx.x, wave = tid >> 6, lane = tid & 63;
  const int bid = blockIdx.x;
  const int b = bid / (NH * 8);
  const int h = (bid / 8) % NH;
  const int jj = bid & 7;              // pair index: q-tiles (15-jj, jj)
  const int kvh = h >> 2;
  const int lr = lane & 15, hi = lane >> 4;
  const f32x4 fz = {0.f, 0.f, 0.f, 0.f};

  const __bf16* kbase = Kk + (size_t)(b * NKV + kvh) * Ss * HD;
  const __bf16* vbase = Vt + (size_t)(b * NKV + kvh) * HD * Ss;

  // staging coords (segment-invariant): waves 0-1 stage K, waves 2-3 stage V.
  const __bf16* srun;
  int soff[8], sldso[8], sstep;
  char* ldsbase;
  if (wave < 2) {
#pragma unroll
    for (int i = 0; i < 8; i++) {
      int cidx = wave * 8 + i;
      int r = cidx * 4 + (lane >> 4);  // key row 0..63
      soff[i] = r * HD + (((lane & 15) ^ (r & 15)) << 3);
      sldso[i] = cidx << 10;
    }
    sstep = 64 * HD;
    ldsbase = (char*)Kl;
  } else {
#pragma unroll
    for (int i = 0; i < 8; i++) {
      int cc = (wave - 2) * 8 + i;
      int r = cc * 8 + (lane >> 3);    // d row 0..127
      soff[i] = r * Ss + (((lane & 7) ^ (r & 7)) << 3);
      sldso[i] = cc << 10;
    }
    sstep = 64;
    ldsbase = (char*)Vl;
  }

  auto STAGE = [&](int buf) {
    char* dbase = ldsbase + (buf << 14);
#pragma unroll
    for (int i = 0; i < 8; i++) gload_lds16(srun + soff[i], dbase + sldso[i]);
    srun += sstep;
  };

  char* pw = (char*)Pl[wave];

  for (int s = 0; s < 2; ++s) {
    const int qb = s ? jj : (15 - jj);  // heavy tile first (light KV subset, L2-warm)
    const int q0 = qb * 128;
    const int wrow0 = q0 + wave * 32;   // this wave's first q row

    // Q rows q0 + wave*32 + g*16 + lr (pre-scaled by SC2 -> scores in log2)
    bf16x8 qf[2][4];
#pragma unroll
    for (int g = 0; g < 2; g++) {
      const __bf16* qbase =
          Q + ((size_t)(b * NH + h) * Ss + wrow0 + g * 16 + lr) * HD;
#pragma unroll
      for (int dc = 0; dc < 4; dc++)
        qf[g][dc] = *(const bf16x8*)(qbase + dc * 32 + hi * 8);
    }

    f32x4 oacc[2][8];
#pragma unroll
    for (int g = 0; g < 2; g++)
#pragma unroll
      for (int i = 0; i < 8; i++) oacc[g][i] = fz;
    float m_[2] = {-1e30f, -1e30f}, l_[2] = {0.f, 0.f};

    srun = (wave < 2) ? kbase : vbase;  // ledger reset per segment
    STAGE(0);                           // chunk 0 in flight (8 loads)
    int cur = 0;
    const int nc = 2 * qb + 2;          // chunks of 64 keys

    for (int c = 0; c < nc; ++c) {
      // T4 ledger: issue chunk c+1, then retire exactly chunk c's 8 loads.
      if (c + 1 < nc) {
        STAGE(cur ^ 1);
        VM8();
      } else {
        VM0();
      }
      BAR();                            // chunk c visible to all waves

      const int k0 = c * 64;
      const bool active = (k0 <= wrow0 + 31);  // wave-uniform

      if (active) {
        const char* Kb = (const char*)Kl[cur];
        const char* Vb = (const char*)Vl[cur];

        // S^T = K Q^T : lane (lr,hi) gets keys 16t+4hi+r of q-rows g*16+lr.
        f32x4 st[2][4];
#pragma unroll
        for (int t = 0; t < 4; t++) { st[0][t] = fz; st[1][t] = fz; }
        __builtin_amdgcn_s_setprio(1);
#pragma unroll
        for (int t = 0; t < 4; t++) {
#pragma unroll
          for (int dc = 0; dc < 4; dc++) {
            const bf16x8 kf = *(const bf16x8*)(Kb + (t * 16 + lr) * 256 +
                                               (((dc * 4 + hi) ^ lr) << 4));
            st[0][t] = mfma_bf16(kf, qf[0][dc], st[0][t]);
            st[1][t] = mfma_bf16(kf, qf[1][dc], st[1][t]);
          }
        }
        __builtin_amdgcn_s_setprio(0);

        const bool needMask = (k0 + 63 > wrow0);  // wave-uniform
        float s2[2][4][4];
        float mx[2];
#pragma unroll
        for (int g = 0; g < 2; g++) {
          const int rel = wrow0 + g * 16 + lr - k0;
          float m = -1e30f;
#pragma unroll
          for (int t = 0; t < 4; t++)
#pragma unroll
            for (int r = 0; r < 4; r++) {
              float v = st[g][t][r];  // log2 domain (Q pre-scaled)
              if (needMask && (16 * t + 4 * hi + r > rel)) v = -1e30f;
              s2[g][t][r] = v;
              m = fmaxf(m, v);
            }
          m = fmaxf(m, __shfl_xor(m, 16, 64));
          m = fmaxf(m, __shfl_xor(m, 32, 64));
          mx[g] = m;
        }

        // defer-max (T13): O-rescale only when running max grows by > 8
        if (__any((mx[0] > m_[0] + 8.f) || (mx[1] > m_[1] + 8.f))) {
#pragma unroll
          for (int g = 0; g < 2; g++) {
            float mn = fmaxf(m_[g], mx[g]);
            float al = exp2f(m_[g] - mn);
            l_[g] *= al;
            m_[g] = mn;
            float alr[4];
#pragma unroll
            for (int r = 0; r < 4; r++) alr[r] = __shfl(al, hi * 4 + r, 64);
#pragma unroll
            for (int dt = 0; dt < 8; dt++)
#pragma unroll
              for (int r = 0; r < 4; r++) oacc[g][dt][r] *= alr[r];
          }
        }

#pragma unroll
        for (int g = 0; g < 2; g++) {
          float rs = 0.f;
          const int rp = g * 16 + lr;  // rp&7 == lr&7
#pragma unroll
          for (int t = 0; t < 4; t++) {
            float p0 = exp2f(s2[g][t][0] - m_[g]), p1 = exp2f(s2[g][t][1] - m_[g]);
            float p2 = exp2f(s2[g][t][2] - m_[g]), p3 = exp2f(s2[g][t][3] - m_[g]);
            rs += (p0 + p1) + (p2 + p3);
            bf16x4 pv = {(__bf16)p0, (__bf16)p1, (__bf16)p2, (__bf16)p3};
            *(bf16x4*)(pw + rp * 128 + (((2 * t + (hi >> 1)) ^ (lr & 7)) << 4) +
                       (hi & 1) * 8) = pv;
          }
          rs += __shfl_xor(rs, 16, 64);
          rs += __shfl_xor(rs, 32, 64);
          l_[g] += rs;
        }

        // PV: vf read ONCE per (dt,kc), used by both q-groups.
        bf16x8 pf[2][2];
#pragma unroll
        for (int g = 0; g < 2; g++)
#pragma unroll
          for (int kc = 0; kc < 2; kc++)
            pf[g][kc] = *(const bf16x8*)(pw + (g * 16 + lr) * 128 +
                                         (((4 * kc + hi) ^ (lr & 7)) << 4));
        __builtin_amdgcn_s_setprio(1);
#pragma unroll
        for (int dt = 0; dt < 8; dt++) {
#pragma unroll
          for (int kc = 0; kc < 2; kc++) {
            const bf16x8 vf = *(const bf16x8*)(Vb + (dt * 16 + lr) * 128 +
                                               (((kc * 4 + hi) ^ (lr & 7)) << 4));
            oacc[0][dt] = mfma_bf16(pf[0][kc], vf, oacc[0][dt]);
            oacc[1][dt] = mfma_bf16(pf[1][kc], vf, oacc[1][dt]);
          }
        }
        __builtin_amdgcn_s_setprio(0);
      }

      BAR();  // WAR: all waves done reading buf cur (next STAGE overwrites)
      cur ^= 1;
    }

    // epilogue for this q-tile
#pragma unroll
    for (int g = 0; g < 2; g++) {
      float rl[4];
#pragma unroll
      for (int r = 0; r < 4; r++) rl[r] = __shfl(l_[g], hi * 4 + r, 64);
#pragma unroll
      for (int dt = 0; dt < 8; dt++) {
#pragma unroll
        for (int r = 0; r < 4; r++) {
          int row = wrow0 + g * 16 + hi * 4 + r;
          Oa[((size_t)(b * Ss) + row) * QSZ + h * HD + dt * 16 + lr] =
              (__bf16)(oacc[g][dt][r] / rl[r]);
        }
      }
    }
  }
}

extern "C" void kernel_launch(void* const* d_in, const int* in_sizes, int n_in,
                              void* d_out, int out_size, void* d_ws, size_t ws_size,
                              hipStream_t stream) {
  const int* positions = (const int*)d_in[0];
  const float* hidden = (const float*)d_in[1];
  const float* w_qkv = (const float*)d_in[2];
  const float* b_qkv = (const float*)d_in[3];
  const float* w_o = (const float*)d_in[4];
  float* out = (float*)d_out;

  char* ws = (char*)d_ws;
  __bf16* hs = (__bf16*)(ws);
  __bf16* wqkvT = (__bf16*)(ws + 33554432);
  __bf16* woT = (__bf16*)(ws + 83886080);
  __bf16* qkv = (__bf16*)(ws + 117440512);
  __bf16* q = (__bf16*)(ws + 167772160);
  __bf16* k = (__bf16*)(ws + 201326592);
  __bf16* vt = (__bf16*)(ws + 209715200);
  __bf16* attn = hs;            // hs dead after gemm1; reuse for attention output
  float* rtab = (float*)(ws);   // 1MB cos/sin table in the hs region: written
                                // AFTER gemm1 consumed hs, consumed by rope_qk,
                                // overwritten later by attn output. 

  f2b<<<2048, 256, 0, stream>>>(hidden, hs, (long)MTOT * HIDDEN / 4);
  transpose_conv<<<(HIDDEN / 64) * (QKV_N / 64), 256, 0, stream>>>(w_qkv, wqkvT, HIDDEN, QKV_N);
  transpose_conv<<<(QSZ / 64) * (HIDDEN / 64), 256, 0, stream>>>(w_o, woT, QSZ, HIDDEN);
  // QKV: tile 256x384, ring-3 (120KB), grid 16*16=256 = ONE balanced pass
  gemm_t<8, 6, 3, 2><<<(MTOT / 256) * (QKV_N / 384), 512, 122880, stream>>>(
      hs, wqkvT, b_qkv, qkv, MTOT, QKV_N, HIDDEN, 1);
  rope_tab<<<Ss, 64, 0, stream>>>(positions, rtab);
  rope_qk<<<Bb * Ss, 256, 0, stream>>>(qkv, rtab, q, k);
  vtrans<<<Bb * NKV * (Ss / 64), 256, 0, stream>>>(qkv, vt);
  // attn: pair-balanced grid, 512 blocks = one balanced pass at 2 blocks/CU
  attn_fwd<<<Bb * NH * 8, 256, 0, stream>>>(q, k, vt, attn);
  // O-proj: tile 256x256, grid 16*16=256 = 1 balanced pass, ring-4 (128KB)
  gemm_t<8, 4, 4, 3><<<(MTOT / 256) * (QSZ / 256), 512, 131072, stream>>>(
      attn, woT, nullptr, out, MTOT, QSZ, QSZ, 0);
}